// Round 7
// baseline (333.074 us; speedup 1.0000x reference)
//
#include <hip/hip_runtime.h>
#include <hip/hip_bf16.h>

typedef __hip_bfloat16 bf16;
typedef __attribute__((ext_vector_type(8))) short bf16x8;   // 8 bf16 = 4 VGPRs
typedef __attribute__((ext_vector_type(4))) float f32x4;
typedef __attribute__((ext_vector_type(16))) float f32x16;

constexpr int Bc  = 2;
constexpr int Sc  = 2048;
constexpr int Dc  = 1024;
constexpr int Hc  = 16;
constexpr int DHc = 64;
constexpr int BS  = Bc * Sc;   // 4096 rows
constexpr int NT  = Sc / 64;   // 32 key tiles

__device__ __forceinline__ float bs2f(unsigned short u) {
    union { unsigned int i; float f; } v; v.i = ((unsigned int)u) << 16; return v.f;
}
__device__ __forceinline__ short f2bs(float x) {
    bf16 h = __float2bfloat16(x);
    return *reinterpret_cast<short*>(&h);
}

// async global->LDS, 16B per lane. LDS dest is wave-uniform base + lane*16.
typedef const __attribute__((address_space(1))) unsigned int* as1_u32p;
typedef __attribute__((address_space(3))) unsigned int* as3_u32p;
__device__ __forceinline__ void gl_lds16(const void* g, void* l) {
    __builtin_amdgcn_global_load_lds((as1_u32p)g, (as3_u32p)l, 16, 0, 0);
}

// ---------------------------------------------------------------------------
// cast x (f32) -> bf16, same layout
// ---------------------------------------------------------------------------
__global__ __launch_bounds__(256) void cast_x(const float* __restrict__ in,
                                              short* __restrict__ out) {
    const int i = (blockIdx.x * 256 + threadIdx.x) * 4;
    const float4 v = *(const float4*)(in + i);
    ushort4 o;
    o.x = (unsigned short)f2bs(v.x);
    o.y = (unsigned short)f2bs(v.y);
    o.z = (unsigned short)f2bs(v.z);
    o.w = (unsigned short)f2bs(v.w);
    *(ushort4*)(out + i) = o;
}

// ---------------------------------------------------------------------------
// transpose + cast: in f32 [1024 k][1024 n] -> out bf16 [n][k].  z picks W.
// ---------------------------------------------------------------------------
__global__ __launch_bounds__(256) void transpose_cast(
    const float* __restrict__ w0, const float* __restrict__ w1,
    const float* __restrict__ w2, const float* __restrict__ w3,
    short* __restrict__ outbase)
{
    __shared__ float T[64][65];
    const int z = blockIdx.z;
    const float* in = (z == 0) ? w0 : (z == 1) ? w1 : (z == 2) ? w2 : w3;
    short* out = outbase + (size_t)z * 1024 * 1024;
    const int k0 = blockIdx.x * 64, n0 = blockIdx.y * 64;
    const int t = threadIdx.x;
    #pragma unroll
    for (int it = 0; it < 4; ++it) {
        const int s = it * 256 + t;
        const int r = s >> 4, c = (s & 15) * 4;
        *(float4*)&T[r][c] = *(const float4*)(in + (size_t)(k0 + r) * 1024 + n0 + c);
    }
    __syncthreads();
    #pragma unroll
    for (int it = 0; it < 4; ++it) {
        const int s = it * 256 + t;
        const int rr = s >> 4, cc = (s & 15) * 4;   // rr: n-local, cc: k-local
        ushort4 o;
        o.x = (unsigned short)f2bs(T[cc + 0][rr]);
        o.y = (unsigned short)f2bs(T[cc + 1][rr]);
        o.z = (unsigned short)f2bs(T[cc + 2][rr]);
        o.w = (unsigned short)f2bs(T[cc + 3][rr]);
        *(ushort4*)(out + (size_t)(n0 + rr) * 1024 + k0 + cc) = o;
    }
}

// ---------------------------------------------------------------------------
// MFMA GEMM (m97 structure): C[z] = (A @ BT[z]^T + bias[z]) * (z==0 ? sc0 : 1)
// 128x128 tile, BK=64, 256 thr = 4 waves of 64x64.
// sc0 folds the attention softmax scale (0.125*log2e) into Q at no cost.
// ---------------------------------------------------------------------------
__global__ __launch_bounds__(256, 3) void gemm_bt(
    const short* __restrict__ A, const short* __restrict__ BTbase,
    const float* __restrict__ b0, const float* __restrict__ b1,
    const float* __restrict__ b2, short* __restrict__ Cbase,
    const float sc0)
{
    __shared__ __align__(16) short As[128 * 64];
    __shared__ __align__(16) short Bs[128 * 64];

    const int z = blockIdx.z;
    const short* BT = BTbase + (size_t)z * 1024 * 1024;
    const float* bias = (z == 0) ? b0 : (z == 1) ? b1 : b2;
    const float sc = (z == 0) ? sc0 : 1.0f;
    short* C = Cbase + (size_t)z * BS * Dc;

    const int t = threadIdx.x;
    const int lane = t & 63, w = t >> 6;
    const int quad = lane >> 4, l16 = lane & 15;
    const int wm = (w & 1) * 64, wn = (w >> 1) * 64;
    const int row0 = blockIdx.y * 128;
    const int col0 = blockIdx.x * 128;
    const int sw = l16 & 7;   // fragment-read swizzle key (row & 7)

    f32x4 acc[4][4] = {};

    for (int kt = 0; kt < 1024; kt += 64) {
        __syncthreads();
        #pragma unroll
        for (int i = 0; i < 4; ++i) {
            const int f = i * 256 + t;            // 16B slot index 0..1023
            const int r = f >> 3;                 // tile row 0..127
            const int g = (f & 7) ^ (r & 7);      // swizzled global seg
            short* lb = &As[(i * 256 + w * 64) * 8];   // wave-uniform base
            gl_lds16(A + (size_t)(row0 + r) * 1024 + kt + g * 8, lb);
            short* lb2 = &Bs[(i * 256 + w * 64) * 8];
            gl_lds16(BT + (size_t)(col0 + r) * 1024 + kt + g * 8, lb2);
        }
        __syncthreads();   // drains vmcnt before use
        #pragma unroll
        for (int ks = 0; ks < 2; ++ks) {
            bf16x8 av[4], bv[4];
            #pragma unroll
            for (int mt = 0; mt < 4; ++mt) {
                const int r = wm + mt * 16 + l16;
                av[mt] = *(const bf16x8*)&As[r * 64 + ((ks * 4 + quad) ^ sw) * 8];
            }
            #pragma unroll
            for (int nt = 0; nt < 4; ++nt) {
                const int r = wn + nt * 16 + l16;
                bv[nt] = *(const bf16x8*)&Bs[r * 64 + ((ks * 4 + quad) ^ sw) * 8];
            }
            #pragma unroll
            for (int mt = 0; mt < 4; ++mt)
                #pragma unroll
                for (int nt = 0; nt < 4; ++nt)
                    acc[mt][nt] = __builtin_amdgcn_mfma_f32_16x16x32_bf16(
                        av[mt], bv[nt], acc[mt][nt], 0, 0, 0);
        }
    }

    float bvv[4];
    #pragma unroll
    for (int nt = 0; nt < 4; ++nt) bvv[nt] = bias[col0 + wn + nt * 16 + l16];
    #pragma unroll
    for (int mt = 0; mt < 4; ++mt)
        #pragma unroll
        for (int reg = 0; reg < 4; ++reg) {
            const size_t row = row0 + wm + mt * 16 + quad * 4 + reg;
            #pragma unroll
            for (int nt = 0; nt < 4; ++nt) {
                const int col = col0 + wn + nt * 16 + l16;
                C[row * 1024 + col] = f2bs((acc[mt][nt][reg] + bvv[nt]) * sc);
            }
        }
}

// ---------------------------------------------------------------------------
// 32x32-MFMA flash attention, strict-upper mask (attend j > i).
// 1024 blocks x 256 thr = 4 waves. Wave (g = w&1, r = w>>1):
//   QK:  rows r*32..+31 x keys g*32..+31 over d=64 (4 mfma_32x32x16)
//   PV:  rows r*32..+31 x d-half g over ALL 64 keys (4 mfma) -> O complete,
//        no cross-wave O merge; only l merges (epilogue, plain add).
// Frag layouts: A[m=lane&31][k=(lane>>5)*8+j]; B[k=(lane>>5)*8+j][n=lane&31]
// (B stored [n][k] row-major => contiguous 16B); C/D col=lane&31,
// row=(reg&3)+8*(reg>>2)+4*(lane>>5)  [HW-validated m74/m101].
// LDS: Ks single (staged during PV: QK reads drained at bar1), VsT double,
// P single per r-half => 36.9KB -> 4 blocks/CU = 16 waves/CU resident.
// All arrays [row][72-pad] with 16B-unit XOR swizzle (unit ^= row&7): the
// 32-row column reads are 4-way conflicted unswizzled (stride-36 banks).
// 2 barriers/tile. XCD remap + {c,31-c,c,31-c} j-map (R4/R6 lessons).
// Row S-1 (fully masked -> reference uniform softmax) fixed by vmean.
// ---------------------------------------------------------------------------
__global__ __launch_bounds__(256, 4) void attn_mfma(
    const short* __restrict__ Qg, const short* __restrict__ Kg,
    const short* __restrict__ Vg, short* __restrict__ CTX)
{
    __shared__ __align__(16) short Ks[64 * 72];        // [key][d]   9216 B
    __shared__ __align__(16) short Vs[2][64 * 72];     // [buf][d][key] 18432 B
    __shared__ __align__(16) short Ps[2][32 * 72];     // [r][q][key]  9216 B
    __shared__ float lred[2][2][32];                   // [g][r][qlocal] 512 B

    const int tid  = threadIdx.x;
    const int lane = tid & 63, w = tid >> 6;           // w 0..3
    const int n32  = lane & 31, hh = lane >> 5;
    const int g    = w & 1, r = w >> 1;

    // XCD-locality remap + CU-balanced q map (R6)
    const int f   = blockIdx.x + 32 * blockIdx.y + 512 * blockIdx.z;  // 0..1023
    const int xcd = f & 7;
    const int loc = f >> 3;            // 0..127 within XCD
    const int j   = loc >> 5;          // 0..3
    const int lq  = loc & 31;
    const int myq = (j & 1) ? (NT - 1 - lq) : lq;
    const int bh  = xcd * 4 + j;
    const int h   = bh & 15;
    const int b   = bh >> 4;
    const size_t rb = (size_t)b * Sc;
    const int cb = h * DHc;

    const int t0 = myq;
    const int q0 = myq * 64;

    // Q fragments: A[m=n32][k=(hh)*8+j + kstep*16], rows q0+r*32+n32
    bf16x8 qf[4];
    {
        const short* qp = Qg + (rb + q0 + r * 32 + n32) * (size_t)Dc + cb + hh * 8;
        #pragma unroll
        for (int k = 0; k < 4; ++k) qf[k] = *(const bf16x8*)(qp + k * 16);
    }

    float l[16] = {};
    f32x16 O = {};

    // staging role: thread stages key row skey, 16B-units u1 & u1+4 (K) and
    // d rows sseg..+7 / +32..+39 at key col skey (V)
    const int skey = tid & 63, u1 = tid >> 6, sseg = u1 * 8;
    const int sk7 = skey & 7;

    {   // prologue: stage tile t0 into Ks and Vs[0]
        const size_t ga = (rb + t0 * 64 + skey) * (size_t)Dc + cb + sseg;
        const bf16x8 k0v = *(const bf16x8*)(Kg + ga);
        const bf16x8 k1v = *(const bf16x8*)(Kg + ga + 32);
        const bf16x8 v0v = *(const bf16x8*)(Vg + ga);
        const bf16x8 v1v = *(const bf16x8*)(Vg + ga + 32);
        short* Krow = &Ks[skey * 72];
        *(bf16x8*)&Krow[(u1 ^ sk7) * 8]       = k0v;
        *(bf16x8*)&Krow[((u1 + 4) ^ sk7) * 8] = k1v;
        #pragma unroll
        for (int e = 0; e < 8; ++e) {
            const int d0 = sseg + e, d1 = d0 + 32;
            Vs[0][d0 * 72 + ((((skey >> 3) ^ e) << 3) | sk7 ? 0 : 0) + (((skey >> 3) ^ (d0 & 7)) << 3) + (skey & 7) - ((((skey >> 3) ^ e) << 3) | sk7 ? 0 : 0)] = v0v[e];
            Vs[0][d1 * 72 + (((skey >> 3) ^ (d1 & 7)) << 3) + (skey & 7)] = v1v[e];
        }
    }
    __syncthreads();

    int cur = 0;
    const int key = g * 32 + n32;      // this wave's QK key column
    const int k7  = key & 7;
    const int n7  = n32 & 7;

    for (int t = t0; t < NT; ++t) {
        const bool havenext = (t + 1 < NT);
        bf16x8 pk0, pk1, pv0, pv1;
        if (havenext) {   // register prefetch of tile t+1
            const size_t ga = (rb + (t + 1) * 64 + skey) * (size_t)Dc + cb + sseg;
            pk0 = *(const bf16x8*)(Kg + ga);
            pk1 = *(const bf16x8*)(Kg + ga + 32);
            pv0 = *(const bf16x8*)(Vg + ga);
            pv1 = *(const bf16x8*)(Vg + ga + 32);
        }

        // ---- QK^T: S[32 rows (r)][32 keys (g)] ----
        f32x16 S = {};
        {
            const short* KsRow = &Ks[key * 72];
            bf16x8 kf[4];
            #pragma unroll
            for (int k = 0; k < 4; ++k)
                kf[k] = *(const bf16x8*)&KsRow[((k * 2 + hh) ^ k7) * 8];
            __builtin_amdgcn_s_setprio(1);
            #pragma unroll
            for (int k = 0; k < 4; ++k)
                S = __builtin_amdgcn_mfma_f32_32x32x16_bf16(qf[k], kf[k], S, 0, 0, 0);
            __builtin_amdgcn_s_setprio(0);
        }

        // ---- softmax (Q pre-scaled; clamp 115.4 ~ old exp(<=80); mask -126) ----
        short* Pr = &Ps[r][0];
        if (t == t0) {
            #pragma unroll
            for (int reg = 0; reg < 16; ++reg) {
                const int qloc = (reg & 3) + 8 * (reg >> 2) + 4 * hh;
                const int col = t * 64 + key;
                const int row = q0 + r * 32 + qloc;
                float s = fminf(S[reg], 115.4f);
                s = (col > row) ? s : -126.0f;
                const float p = exp2f(s);
                l[reg] += p;
                const int unit = (g * 4 + (n32 >> 3)) ^ (qloc & 7);
                Pr[qloc * 72 + unit * 8 + n7] = f2bs(p);
            }
        } else {
            #pragma unroll
            for (int reg = 0; reg < 16; ++reg) {
                const int qloc = (reg & 3) + 8 * (reg >> 2) + 4 * hh;
                const float p = exp2f(fminf(S[reg], 115.4f));
                l[reg] += p;
                const int unit = (g * 4 + (n32 >> 3)) ^ (qloc & 7);
                Pr[qloc * 72 + unit * 8 + n7] = f2bs(p);
            }
        }

        __syncthreads();   // bar1: P complete; all QK reads of Ks drained

        // ---- PV: O[32 rows (r)][32 d (g)] over all 64 keys ----
        {
            const int d = g * 32 + n32;          // d&7 == n7
            const short* Vrow = &Vs[cur][d * 72];
            const short* Prow = &Ps[r][n32 * 72];
            bf16x8 pf[4], vf[4];
            #pragma unroll
            for (int k = 0; k < 4; ++k) {
                const int off = ((k * 2 + hh) ^ n7) * 8;
                pf[k] = *(const bf16x8*)&Prow[off];
                vf[k] = *(const bf16x8*)&Vrow[off];
            }
            __builtin_amdgcn_s_setprio(1);
            #pragma unroll
            for (int k = 0; k < 4; ++k)
                O = __builtin_amdgcn_mfma_f32_32x32x16_bf16(pf[k], vf[k], O, 0, 0, 0);
            __builtin_amdgcn_s_setprio(0);
        }

        if (havenext) {   // stage t+1: K into Ks (QK done), V into other buf
            short* Krow = &Ks[skey * 72];
            *(bf16x8*)&Krow[(u1 ^ sk7) * 8]       = pk0;
            *(bf16x8*)&Krow[((u1 + 4) ^ sk7) * 8] = pk1;
            short* Vn = &Vs[cur ^ 1][0];
            #pragma unroll
            for (int e = 0; e < 8; ++e) {
                const int d0 = sseg + e, d1 = d0 + 32;
                Vn[d0 * 72 + (((skey >> 3) ^ (d0 & 7)) << 3) + (skey & 7)] = pv0[e];
                Vn[d1 * 72 + (((skey >> 3) ^ (d1 & 7)) << 3) + (skey & 7)] = pv1[e];
            }
            __syncthreads();   // bar2: staging visible; P/V reads drained
            cur ^= 1;
        }
    }

    // ---- epilogue: reduce l over the wave's 32 key-lanes, merge across g ----
    #pragma unroll
    for (int off = 1; off < 32; off <<= 1)
        #pragma unroll
        for (int reg = 0; reg < 16; ++reg)
            l[reg] += __shfl_xor(l[reg], off, 64);
    if (n32 == 0) {
        #pragma unroll
        for (int reg = 0; reg < 16; ++reg)
            lred[g][r][(reg & 3) + 8 * (reg >> 2) + 4 * hh] = l[reg];
    }
    __syncthreads();
    #pragma unroll
    for (int reg = 0; reg < 16; ++reg) {
        const int qloc = (reg & 3) + 8 * (reg >> 2) + 4 * hh;
        const float inv = 1.0f / (lred[0][r][qloc] + lred[1][r][qloc]);
        const size_t row = rb + q0 + r * 32 + qloc;
        CTX[row * Dc + cb + g * 32 + n32] = f2bs(O[reg] * inv);
    }
}

// ---------------------------------------------------------------------------
// Row S-1 fully masked: reference softmax of all-(-1e9) is exactly uniform
// 1/S -> ctx = mean_j V[b,j,h,:]. Overwrites attn's placeholder.
// ---------------------------------------------------------------------------
__global__ __launch_bounds__(256) void vmean(const short* __restrict__ V,
                                             short* __restrict__ CTX)
{
    const int h = blockIdx.x, b = blockIdx.y;
    const int t = threadIdx.x;
    const int dh = t & 63, ck = t >> 6;      // 4 chunks of 512 keys
    float s = 0.f;
    const short* vp = V + ((size_t)b * Sc + ck * 512) * Dc + h * DHc + dh;
    for (int j = 0; j < 512; ++j) s += bs2f(vp[(size_t)j * Dc]);
    __shared__ float red[4][64];
    red[ck][dh] = s;
    __syncthreads();
    if (ck == 0) {
        const float tot = (red[0][dh] + red[1][dh] + red[2][dh] + red[3][dh]) * (1.f / Sc);
        CTX[((size_t)b * Sc + Sc - 1) * Dc + h * DHc + dh] = f2bs(tot);
    }
}

// ---------------------------------------------------------------------------
// out = LayerNorm(x + attn_out) * gamma + beta; x f32, AO bf16, out f32
// ---------------------------------------------------------------------------
__global__ __launch_bounds__(256, 4) void resid_ln(
    const float* __restrict__ X, const short* __restrict__ AO,
    const float* __restrict__ gamma, const float* __restrict__ beta,
    float* __restrict__ out)
{
    const int r = blockIdx.x;
    const int t = threadIdx.x;
    const size_t base = (size_t)r * Dc + t * 4;

    const float4 x4 = *(const float4*)(X + base);
    const ushort4 a4 = *(const ushort4*)(AO + base);
    float y[4];
    y[0] = x4.x + bs2f(a4.x);
    y[1] = x4.y + bs2f(a4.y);
    y[2] = x4.z + bs2f(a4.z);
    y[3] = x4.w + bs2f(a4.w);

    float s  = y[0] + y[1] + y[2] + y[3];
    float s2 = y[0]*y[0] + y[1]*y[1] + y[2]*y[2] + y[3]*y[3];
    #pragma unroll
    for (int off = 1; off < 64; off <<= 1) {
        s  += __shfl_xor(s,  off, 64);
        s2 += __shfl_xor(s2, off, 64);
    }
    __shared__ float red[8];
    const int w = t >> 6;
    if ((t & 63) == 0) { red[w] = s; red[4 + w] = s2; }
    __syncthreads();
    s  = red[0] + red[1] + red[2] + red[3];
    s2 = red[4] + red[5] + red[6] + red[7];

    const float mu   = s * (1.0f / Dc);
    const float rstd = rsqrtf(s2 * (1.0f / Dc) - mu * mu + 1e-6f);

    const float4 g4 = *(const float4*)(gamma + t * 4);
    const float4 b4 = *(const float4*)(beta  + t * 4);
    float4 o;
    o.x = (y[0] - mu) * rstd * g4.x + b4.x;
    o.y = (y[1] - mu) * rstd * g4.y + b4.y;
    o.z = (y[2] - mu) * rstd * g4.z + b4.z;
    o.w = (y[3] - mu) * rstd * g4.w + b4.w;
    *(float4*)(out + base) = o;
}

// ---------------------------------------------------------------------------
extern "C" void kernel_launch(void* const* d_in, const int* in_sizes, int n_in,
                              void* d_out, int out_size, void* d_ws, size_t ws_size,
                              hipStream_t stream)
{
    (void)in_sizes; (void)n_in; (void)out_size; (void)ws_size;
    const float* x     = (const float*)d_in[0];
    const float* Wq    = (const float*)d_in[1];
    const float* bq    = (const float*)d_in[2];
    const float* Wk    = (const float*)d_in[3];
    const float* bk    = (const float*)d_in[4];
    const float* Wv    = (const float*)d_in[5];
    const float* bv    = (const float*)d_in[6];
    const float* Wo    = (const float*)d_in[7];
    const float* bo    = (const float*)d_in[8];
    const float* gamma = (const float*)d_in[9];
    const float* beta  = (const float*)d_in[10];
    float* out = (float*)d_out;

    const size_t matN = (size_t)BS * Dc;       // 4,194,304
    const size_t wN   = (size_t)Dc * Dc;       // 1,048,576
    short* xb = (short*)d_ws;                  // 8 MB
    short* WT = xb + matN;                     // 8 MB (4 transposed weights)
    short* Qb = WT + 4 * wN;                   // 8 MB
    short* Kb = Qb + matN;                     // 8 MB
    short* Vb = Kb + matN;                     // 8 MB
    short* Cx = Vb + matN;                     // 8 MB
    short* AO = Qb;                            // Q dead after attention

    cast_x<<<matN / 1024, 256, 0, stream>>>(x, xb);

    dim3 gt(16, 16, 4);
    transpose_cast<<<gt, 256, 0, stream>>>(Wq, Wk, Wv, Wo, WT);

    dim3 gq(Dc / 128, BS / 128, 3);            // (8, 32, 3)
    gemm_bt<<<gq, 256, 0, stream>>>(xb, WT, bq, bk, bv, Qb, 0.18033688f);

    dim3 ga(32, 16, 2);                        // 1024 blocks, remapped inside
    attn_mfma<<<ga, 256, 0, stream>>>(Qb, Kb, Vb, Cx);

    dim3 gv(Hc, Bc);
    vmean<<<gv, 256, 0, stream>>>(Vb, Cx);     // fix up row S-1 (uniform softmax)

    dim3 go(Dc / 128, BS / 128, 1);
    gemm_bt<<<go, 256, 0, stream>>>(Cx, WT + 3 * wN, bo, bo, bo, AO, 1.0f);

    resid_ln<<<BS, 256, 0, stream>>>(x, AO, gamma, beta, out);
}

// Round 8
// 214.011 us; speedup vs baseline: 1.5563x; 1.5563x over previous
//
#include <hip/hip_runtime.h>
#include <hip/hip_bf16.h>

typedef __hip_bfloat16 bf16;
typedef __attribute__((ext_vector_type(8))) short bf16x8;   // 8 bf16 = 4 VGPRs
typedef __attribute__((ext_vector_type(4))) float f32x4;

constexpr int Bc  = 2;
constexpr int Sc  = 2048;
constexpr int Dc  = 1024;
constexpr int Hc  = 16;
constexpr int DHc = 64;
constexpr int BS  = Bc * Sc;   // 4096 rows
constexpr int NT  = Sc / 64;   // 32 key tiles

__device__ __forceinline__ float bs2f(unsigned short u) {
    union { unsigned int i; float f; } v; v.i = ((unsigned int)u) << 16; return v.f;
}
__device__ __forceinline__ short f2bs(float x) {
    bf16 h = __float2bfloat16(x);
    return *reinterpret_cast<short*>(&h);
}

// async global->LDS, 16B per lane. LDS dest is wave-uniform base + lane*16.
typedef const __attribute__((address_space(1))) unsigned int* as1_u32p;
typedef __attribute__((address_space(3))) unsigned int* as3_u32p;
__device__ __forceinline__ void gl_lds16(const void* g, void* l) {
    __builtin_amdgcn_global_load_lds((as1_u32p)g, (as3_u32p)l, 16, 0, 0);
}

// ---------------------------------------------------------------------------
// cast x (f32) -> bf16, same layout
// ---------------------------------------------------------------------------
__global__ __launch_bounds__(256) void cast_x(const float* __restrict__ in,
                                              short* __restrict__ out) {
    const int i = (blockIdx.x * 256 + threadIdx.x) * 4;
    const float4 v = *(const float4*)(in + i);
    ushort4 o;
    o.x = (unsigned short)f2bs(v.x);
    o.y = (unsigned short)f2bs(v.y);
    o.z = (unsigned short)f2bs(v.z);
    o.w = (unsigned short)f2bs(v.w);
    *(ushort4*)(out + i) = o;
}

// ---------------------------------------------------------------------------
// transpose + cast: in f32 [1024 k][1024 n] -> out bf16 [n][k].  z picks W.
// ---------------------------------------------------------------------------
__global__ __launch_bounds__(256) void transpose_cast(
    const float* __restrict__ w0, const float* __restrict__ w1,
    const float* __restrict__ w2, const float* __restrict__ w3,
    short* __restrict__ outbase)
{
    __shared__ float T[64][65];
    const int z = blockIdx.z;
    const float* in = (z == 0) ? w0 : (z == 1) ? w1 : (z == 2) ? w2 : w3;
    short* out = outbase + (size_t)z * 1024 * 1024;
    const int k0 = blockIdx.x * 64, n0 = blockIdx.y * 64;
    const int t = threadIdx.x;
    #pragma unroll
    for (int it = 0; it < 4; ++it) {
        const int s = it * 256 + t;
        const int r = s >> 4, c = (s & 15) * 4;
        *(float4*)&T[r][c] = *(const float4*)(in + (size_t)(k0 + r) * 1024 + n0 + c);
    }
    __syncthreads();
    #pragma unroll
    for (int it = 0; it < 4; ++it) {
        const int s = it * 256 + t;
        const int rr = s >> 4, cc = (s & 15) * 4;   // rr: n-local, cc: k-local
        ushort4 o;
        o.x = (unsigned short)f2bs(T[cc + 0][rr]);
        o.y = (unsigned short)f2bs(T[cc + 1][rr]);
        o.z = (unsigned short)f2bs(T[cc + 2][rr]);
        o.w = (unsigned short)f2bs(T[cc + 3][rr]);
        *(ushort4*)(out + (size_t)(n0 + rr) * 1024 + k0 + cc) = o;
    }
}

// ---------------------------------------------------------------------------
// MFMA GEMM (m97 structure): C[z] = (A @ BT[z]^T + bias[z]) * (z==0 ? sc0 : 1)
// 128x128 tile, BK=64, 256 thr = 4 waves of 64x64.
// sc0 folds the attention softmax scale (0.125*log2e) into Q at no cost.
// ---------------------------------------------------------------------------
__global__ __launch_bounds__(256, 3) void gemm_bt(
    const short* __restrict__ A, const short* __restrict__ BTbase,
    const float* __restrict__ b0, const float* __restrict__ b1,
    const float* __restrict__ b2, short* __restrict__ Cbase,
    const float sc0)
{
    __shared__ __align__(16) short As[128 * 64];
    __shared__ __align__(16) short Bs[128 * 64];

    const int z = blockIdx.z;
    const short* BT = BTbase + (size_t)z * 1024 * 1024;
    const float* bias = (z == 0) ? b0 : (z == 1) ? b1 : b2;
    const float sc = (z == 0) ? sc0 : 1.0f;
    short* C = Cbase + (size_t)z * BS * Dc;

    const int t = threadIdx.x;
    const int lane = t & 63, w = t >> 6;
    const int quad = lane >> 4, l16 = lane & 15;
    const int wm = (w & 1) * 64, wn = (w >> 1) * 64;
    const int row0 = blockIdx.y * 128;
    const int col0 = blockIdx.x * 128;
    const int sw = l16 & 7;   // fragment-read swizzle key (row & 7)

    f32x4 acc[4][4] = {};

    for (int kt = 0; kt < 1024; kt += 64) {
        __syncthreads();
        #pragma unroll
        for (int i = 0; i < 4; ++i) {
            const int f = i * 256 + t;            // 16B slot index 0..1023
            const int r = f >> 3;                 // tile row 0..127
            const int g = (f & 7) ^ (r & 7);      // swizzled global seg
            short* lb = &As[(i * 256 + w * 64) * 8];   // wave-uniform base
            gl_lds16(A + (size_t)(row0 + r) * 1024 + kt + g * 8, lb);
            short* lb2 = &Bs[(i * 256 + w * 64) * 8];
            gl_lds16(BT + (size_t)(col0 + r) * 1024 + kt + g * 8, lb2);
        }
        __syncthreads();   // drains vmcnt before use
        #pragma unroll
        for (int ks = 0; ks < 2; ++ks) {
            bf16x8 av[4], bv[4];
            #pragma unroll
            for (int mt = 0; mt < 4; ++mt) {
                const int r = wm + mt * 16 + l16;
                av[mt] = *(const bf16x8*)&As[r * 64 + ((ks * 4 + quad) ^ sw) * 8];
            }
            #pragma unroll
            for (int nt = 0; nt < 4; ++nt) {
                const int r = wn + nt * 16 + l16;
                bv[nt] = *(const bf16x8*)&Bs[r * 64 + ((ks * 4 + quad) ^ sw) * 8];
            }
            #pragma unroll
            for (int mt = 0; mt < 4; ++mt)
                #pragma unroll
                for (int nt = 0; nt < 4; ++nt)
                    acc[mt][nt] = __builtin_amdgcn_mfma_f32_16x16x32_bf16(
                        av[mt], bv[nt], acc[mt][nt], 0, 0, 0);
        }
    }

    float bvv[4];
    #pragma unroll
    for (int nt = 0; nt < 4; ++nt) bvv[nt] = bias[col0 + wn + nt * 16 + l16];
    #pragma unroll
    for (int mt = 0; mt < 4; ++mt)
        #pragma unroll
        for (int reg = 0; reg < 4; ++reg) {
            const size_t row = row0 + wm + mt * 16 + quad * 4 + reg;
            #pragma unroll
            for (int nt = 0; nt < 4; ++nt) {
                const int col = col0 + wn + nt * 16 + l16;
                C[row * 1024 + col] = f2bs((acc[mt][nt][reg] + bvv[nt]) * sc);
            }
        }
}

// ---------------------------------------------------------------------------
// Key permutation pi(k) = (k&15)*4 + (k>>4), applied identically to the key
// axis of P and of VsT (sum over k is order-agnostic). Under pi, a thread's
// 4 P-values per output row become phys cols 4*l16+{0..3} -> one
// ds_write_b64 per row + packed cvt instead of 16 b16 writes + 16 RNE chains.
// ---------------------------------------------------------------------------

// softmax(step) + PV for one 16-row q-fragment vs a staged 64-key tile.
// Q is PRE-SCALED by 0.125*log2e in gemm_bt, so scores feed exp2 directly.
// DIAG: only the diagonal tile applies the strict-upper (col > row) mask.
// l-accumulation is done ON THE MATRIX PIPE: lacc = mfma(pf, ones, lacc)
// gives C[row][*] = sum_k P[row][k] (B==1), reusing the pf fragment already
// loaded for PV. Removes 16 VALU adds/step + the entire epilogue shuffle
// reduce (VALU was the dominant busy pipe at 3x MFMA).
// Layouts (HW-validated): A-frag A[m=l16][k=quad*8+j]; B-frag
// B[k=quad*8+j][n=l16]; C/D row=quad*4+reg, col=l16.
template<bool DIAG>
__device__ __forceinline__ void qtile_step(
    const bf16x8 (&qf)[2],
    const short (&Ks)[64][72], const short (&VsT)[64][72],
    short (&Psw)[16][72],
    const int k0, const int row_base,
    const int quad, const int l16,
    const bf16x8 ones,
    f32x4 &lacc, f32x4 (&O)[4])
{
    bf16x8 kf[2][4];
    #pragma unroll
    for (int ks = 0; ks < 2; ++ks)
        #pragma unroll
        for (int nt = 0; nt < 4; ++nt)
            kf[ks][nt] = *(const bf16x8*)&Ks[nt * 16 + l16][ks * 32 + quad * 8];

    f32x4 S[4] = {};
    __builtin_amdgcn_s_setprio(1);
    #pragma unroll
    for (int ks = 0; ks < 2; ++ks)
        #pragma unroll
        for (int nt = 0; nt < 4; ++nt)
            S[nt] = __builtin_amdgcn_mfma_f32_16x16x32_bf16(qf[ks], kf[ks][nt], S[nt], 0, 0, 0);
    __builtin_amdgcn_s_setprio(0);

    // clamp 115.4 == old exp(<=80); mask -126 -> 2^-126 ~= old exp(-87).
    #pragma unroll
    for (int nt = 0; nt < 4; ++nt) {
        #pragma unroll
        for (int reg = 0; reg < 4; ++reg) {
            float s = fminf(S[nt][reg], 115.4f);
            if (DIAG) {
                const int col = k0 + nt * 16 + l16;
                const int row = row_base + quad * 4 + reg;
                s = (col > row) ? s : -126.0f;
            }
            S[nt][reg] = exp2f(s);
        }
    }

    // publish P: per output row, pack 4 values (phys cols 4*l16+0..3) -> b64
    #pragma unroll
    for (int reg = 0; reg < 4; ++reg) {
        const __hip_bfloat162 lo = __float22bfloat162_rn(make_float2(S[0][reg], S[1][reg]));
        const __hip_bfloat162 hi = __float22bfloat162_rn(make_float2(S[2][reg], S[3][reg]));
        uint2 u;
        u.x = *reinterpret_cast<const unsigned int*>(&lo);
        u.y = *reinterpret_cast<const unsigned int*>(&hi);
        *(uint2*)&Psw[quad * 4 + reg][l16 * 4] = u;
    }

    __builtin_amdgcn_s_setprio(1);
    #pragma unroll
    for (int ks = 0; ks < 2; ++ks) {
        const bf16x8 pf = *(const bf16x8*)&Psw[l16][ks * 32 + quad * 8];
        lacc = __builtin_amdgcn_mfma_f32_16x16x32_bf16(pf, ones, lacc, 0, 0, 0);
        #pragma unroll
        for (int nt = 0; nt < 4; ++nt) {
            const bf16x8 vf = *(const bf16x8*)&VsT[nt * 16 + l16][ks * 32 + quad * 8];
            O[nt] = __builtin_amdgcn_mfma_f32_16x16x32_bf16(pf, vf, O[nt], 0, 0, 0);
        }
    }
    __builtin_amdgcn_s_setprio(0);
}

// ---------------------------------------------------------------------------
// Pair-SEQUENTIAL MFMA flash attention (R2 structure, measured best 55.7us),
// strict-upper mask (attend j > i).
// 512 blocks x 256 thr = 4 waves; block runs q-tile p to completion (key
// tiles p..31), then q-tile 31-p: uniform 33 iterations/block, every wave
// computes every iteration. K/V double-buffered, ONE barrier per key tile.
// XCD remap (R4: FETCH 120->12MB): XCD x owns 4 complete (b,h) groups;
// per-CU blocks get identical pair index -> uniform duration.
// l via MFMA ones-trick (see qtile_step); prefetch pointers strength-reduced.
// Row S-1 (fully masked -> reference uniform softmax) fixed by vmean.
// ---------------------------------------------------------------------------
__global__ __launch_bounds__(256, 3) void attn_mfma(
    const short* __restrict__ Qg, const short* __restrict__ Kg,
    const short* __restrict__ Vg, short* __restrict__ CTX)
{
    __shared__ __align__(16) short Ks [2][64][72];   // [buf][key][d]
    __shared__ __align__(16) short VsT[2][64][72];   // [buf][d][pi(key)]
    __shared__ __align__(16) short Ps[4][16][72];    // per-wave P scratch

    const int tid  = threadIdx.x;
    const int lane = tid & 63, w = tid >> 6;         // w 0..3
    const int quad = lane >> 4, l16 = lane & 15;

    // XCD-locality remap (bijective, 512 % 8 == 0)
    const int f  = blockIdx.x + 16 * blockIdx.y + 256 * blockIdx.z;  // 0..511
    const int r_ = (f & 7) * 64 + (f >> 3);
    const int p  = r_ & 15;
    const int h  = (r_ >> 4) & 15;
    const int b  = r_ >> 8;
    const size_t rb = (size_t)b * Sc;
    const int cb = h * DHc;

    // staging: 256 threads; thread stages key row skey, d-segs sseg & sseg+32
    const int skey = tid & 63, sseg = (tid >> 6) * 8;
    const int pkey = ((skey & 15) << 2) | (skey >> 4);   // pi(skey)

    bf16x8 ones;
    #pragma unroll
    for (int e = 0; e < 8; ++e) ones[e] = (short)0x3F80;   // bf16 1.0

    const size_t tstride = (size_t)64 * Dc;

    #pragma unroll 1
    for (int ph = 0; ph < 2; ++ph) {
        const int myq = ph ? (NT - 1 - p) : p;   // q-tile index 0..31
        const int t0  = myq;
        const int q0  = myq * 64;

        bf16x8 qf[2];
        {
            const short* qp = Qg + (rb + q0 + w * 16 + l16) * (size_t)Dc + cb + quad * 8;
            qf[0] = *(const bf16x8*)(qp);
            qf[1] = *(const bf16x8*)(qp + 32);
        }
        f32x4 lacc = {};
        f32x4 O[4] = {};

        // strength-reduced staging pointers (advance by 64*Dc per tile)
        const short* kp = Kg + (rb + (size_t)t0 * 64 + skey) * Dc + cb + sseg;
        const short* vp = Vg + (rb + (size_t)t0 * 64 + skey) * Dc + cb + sseg;

        if (ph) __syncthreads();   // phase A waves may still be reading bufs

        {   // stage first tile t0 into buf t0&1
            const int buf = t0 & 1;
            const bf16x8 k0v = *(const bf16x8*)(kp);
            const bf16x8 k1v = *(const bf16x8*)(kp + 32);
            const bf16x8 v0v = *(const bf16x8*)(vp);
            const bf16x8 v1v = *(const bf16x8*)(vp + 32);
            *(bf16x8*)&Ks[buf][skey][sseg]      = k0v;
            *(bf16x8*)&Ks[buf][skey][sseg + 32] = k1v;
            #pragma unroll
            for (int e = 0; e < 8; ++e) {
                VsT[buf][sseg + e][pkey]      = v0v[e];
                VsT[buf][sseg + 32 + e][pkey] = v1v[e];
            }
        }
        __syncthreads();

        for (int t = t0; t < NT; ++t) {
            const int cur = t & 1;
            const bool havenext = (t + 1 < NT);
            bf16x8 pk0, pk1, pv0, pv1;
            if (havenext) {   // register prefetch of tile t+1
                pk0 = *(const bf16x8*)(kp + tstride);
                pk1 = *(const bf16x8*)(kp + tstride + 32);
                pv0 = *(const bf16x8*)(vp + tstride);
                pv1 = *(const bf16x8*)(vp + tstride + 32);
            }

            if (t == t0)
                qtile_step<true >(qf, Ks[cur], VsT[cur], Ps[w],
                                  t * 64, q0 + w * 16, quad, l16, ones, lacc, O);
            else
                qtile_step<false>(qf, Ks[cur], VsT[cur], Ps[w],
                                  t * 64, q0 + w * 16, quad, l16, ones, lacc, O);

            if (havenext) {   // stage tile t+1 into the other buffer, ONE barrier
                const int nb = cur ^ 1;
                *(bf16x8*)&Ks[nb][skey][sseg]      = pk0;
                *(bf16x8*)&Ks[nb][skey][sseg + 32] = pk1;
                #pragma unroll
                for (int e = 0; e < 8; ++e) {
                    VsT[nb][sseg + e][pkey]      = pv0[e];
                    VsT[nb][sseg + 32 + e][pkey] = pv1[e];
                }
                __syncthreads();
            }
            kp += tstride;
            vp += tstride;
        }

        // normalize + store: lacc[reg] already holds l for row quad*4+reg
        float inv[4];
        #pragma unroll
        for (int reg = 0; reg < 4; ++reg) inv[reg] = 1.0f / lacc[reg];
        #pragma unroll
        for (int nt = 0; nt < 4; ++nt)
            #pragma unroll
            for (int reg = 0; reg < 4; ++reg) {
                const size_t row = rb + q0 + w * 16 + quad * 4 + reg;
                CTX[row * Dc + cb + nt * 16 + l16] = f2bs(O[nt][reg] * inv[reg]);
            }
    }
}

// ---------------------------------------------------------------------------
// Row S-1 fully masked: reference softmax of all-(-1e9) is exactly uniform
// 1/S -> ctx = mean_j V[b,j,h,:]. Overwrites attn's placeholder.
// ---------------------------------------------------------------------------
__global__ __launch_bounds__(256) void vmean(const short* __restrict__ V,
                                             short* __restrict__ CTX)
{
    const int h = blockIdx.x, b = blockIdx.y;
    const int t = threadIdx.x;
    const int dh = t & 63, ck = t >> 6;      // 4 chunks of 512 keys
    float s = 0.f;
    const short* vp = V + ((size_t)b * Sc + ck * 512) * Dc + h * DHc + dh;
    for (int j = 0; j < 512; ++j) s += bs2f(vp[(size_t)j * Dc]);
    __shared__ float red[4][64];
    red[ck][dh] = s;
    __syncthreads();
    if (ck == 0) {
        const float tot = (red[0][dh] + red[1][dh] + red[2][dh] + red[3][dh]) * (1.f / Sc);
        CTX[((size_t)b * Sc + Sc - 1) * Dc + h * DHc + dh] = f2bs(tot);
    }
}

// ---------------------------------------------------------------------------
// out = LayerNorm(x + attn_out) * gamma + beta; x f32, AO bf16, out f32
// ---------------------------------------------------------------------------
__global__ __launch_bounds__(256, 4) void resid_ln(
    const float* __restrict__ X, const short* __restrict__ AO,
    const float* __restrict__ gamma, const float* __restrict__ beta,
    float* __restrict__ out)
{
    const int r = blockIdx.x;
    const int t = threadIdx.x;
    const size_t base = (size_t)r * Dc + t * 4;

    const float4 x4 = *(const float4*)(X + base);
    const ushort4 a4 = *(const ushort4*)(AO + base);
    float y[4];
    y[0] = x4.x + bs2f(a4.x);
    y[1] = x4.y + bs2f(a4.y);
    y[2] = x4.z + bs2f(a4.z);
    y[3] = x4.w + bs2f(a4.w);

    float s  = y[0] + y[1] + y[2] + y[3];
    float s2 = y[0]*y[0] + y[1]*y[1] + y[2]*y[2] + y[3]*y[3];
    #pragma unroll
    for (int off = 1; off < 64; off <<= 1) {
        s  += __shfl_xor(s,  off, 64);
        s2 += __shfl_xor(s2, off, 64);
    }
    __shared__ float red[8];
    const int w = t >> 6;
    if ((t & 63) == 0) { red[w] = s; red[4 + w] = s2; }
    __syncthreads();
    s  = red[0] + red[1] + red[2] + red[3];
    s2 = red[4] + red[5] + red[6] + red[7];

    const float mu   = s * (1.0f / Dc);
    const float rstd = rsqrtf(s2 * (1.0f / Dc) - mu * mu + 1e-6f);

    const float4 g4 = *(const float4*)(gamma + t * 4);
    const float4 b4 = *(const float4*)(beta  + t * 4);
    float4 o;
    o.x = (y[0] - mu) * rstd * g4.x + b4.x;
    o.y = (y[1] - mu) * rstd * g4.y + b4.y;
    o.z = (y[2] - mu) * rstd * g4.z + b4.z;
    o.w = (y[3] - mu) * rstd * g4.w + b4.w;
    *(float4*)(out + base) = o;
}

// ---------------------------------------------------------------------------
extern "C" void kernel_launch(void* const* d_in, const int* in_sizes, int n_in,
                              void* d_out, int out_size, void* d_ws, size_t ws_size,
                              hipStream_t stream)
{
    (void)in_sizes; (void)n_in; (void)out_size; (void)ws_size;
    const float* x     = (const float*)d_in[0];
    const float* Wq    = (const float*)d_in[1];
    const float* bq    = (const float*)d_in[2];
    const float* Wk    = (const float*)d_in[3];
    const float* bk    = (const float*)d_in[4];
    const float* Wv    = (const float*)d_in[5];
    const float* bv    = (const float*)d_in[6];
    const float* Wo    = (const float*)d_in[7];
    const float* bo    = (const float*)d_in[8];
    const float* gamma = (const float*)d_in[9];
    const float* beta  = (const float*)d_in[10];
    float* out = (float*)d_out;

    const size_t matN = (size_t)BS * Dc;       // 4,194,304
    const size_t wN   = (size_t)Dc * Dc;       // 1,048,576
    short* xb = (short*)d_ws;                  // 8 MB
    short* WT = xb + matN;                     // 8 MB (4 transposed weights)
    short* Qb = WT + 4 * wN;                   // 8 MB
    short* Kb = Qb + matN;                     // 8 MB
    short* Vb = Kb + matN;                     // 8 MB
    short* Cx = Vb + matN;                     // 8 MB
    short* AO = Qb;                            // Q dead after attention

    cast_x<<<matN / 1024, 256, 0, stream>>>(x, xb);

    dim3 gt(16, 16, 4);
    transpose_cast<<<gt, 256, 0, stream>>>(Wq, Wk, Wv, Wo, WT);

    dim3 gq(Dc / 128, BS / 128, 3);            // (8, 32, 3)
    gemm_bt<<<gq, 256, 0, stream>>>(xb, WT, bq, bk, bv, Qb, 0.18033688f);

    dim3 ga(16, 16, 2);                        // 512 blocks, XCD-remapped inside
    attn_mfma<<<ga, 256, 0, stream>>>(Qb, Kb, Vb, Cx);

    dim3 gv(Hc, Bc);
    vmean<<<gv, 256, 0, stream>>>(Vb, Cx);     // fix up row S-1 (uniform softmax)

    dim3 go(Dc / 128, BS / 128, 1);
    gemm_bt<<<go, 256, 0, stream>>>(Cx, WT + 3 * wN, bo, bo, bo, AO, 1.0f);

    resid_ln<<<BS, 256, 0, stream>>>(x, AO, gamma, beta, out);
}

// Round 9
// 203.315 us; speedup vs baseline: 1.6382x; 1.0526x over previous
//
#include <hip/hip_runtime.h>
#include <hip/hip_bf16.h>

typedef __hip_bfloat16 bf16;
typedef __attribute__((ext_vector_type(8))) short bf16x8;   // 8 bf16 = 4 VGPRs
typedef __attribute__((ext_vector_type(4))) float f32x4;

constexpr int Bc  = 2;
constexpr int Sc  = 2048;
constexpr int Dc  = 1024;
constexpr int Hc  = 16;
constexpr int DHc = 64;
constexpr int BS  = Bc * Sc;   // 4096 rows
constexpr int NT  = Sc / 64;   // 32 key tiles

__device__ __forceinline__ float bs2f(unsigned short u) {
    union { unsigned int i; float f; } v; v.i = ((unsigned int)u) << 16; return v.f;
}
__device__ __forceinline__ short f2bs(float x) {
    bf16 h = __float2bfloat16(x);
    return *reinterpret_cast<short*>(&h);
}

// async global->LDS, 16B per lane. LDS dest is wave-uniform base + lane*16.
typedef const __attribute__((address_space(1))) unsigned int* as1_u32p;
typedef __attribute__((address_space(3))) unsigned int* as3_u32p;
__device__ __forceinline__ void gl_lds16(const void* g, void* l) {
    __builtin_amdgcn_global_load_lds((as1_u32p)g, (as3_u32p)l, 16, 0, 0);
}

// ---------------------------------------------------------------------------
// prep: fused {cast x f32->bf16} + {transpose+cast 4 weight matrices}.
// Blocks [0,4096): cast chunk; blocks [4096,5120): transpose tile.
// One launch instead of two (non-attn time is 157us and includes ~7 serialized
// launches; this removes one).
// ---------------------------------------------------------------------------
__global__ __launch_bounds__(256) void prep(
    const float* __restrict__ x, short* __restrict__ xb,
    const float* __restrict__ w0, const float* __restrict__ w1,
    const float* __restrict__ w2, const float* __restrict__ w3,
    short* __restrict__ WT)
{
    __shared__ float T[64][65];
    const int i = blockIdx.x;
    const int t = threadIdx.x;

    if (i < 4096) {   // cast path
        const int off = i * 1024 + t * 4;
        const float4 v = *(const float4*)(x + off);
        ushort4 o;
        o.x = (unsigned short)f2bs(v.x);
        o.y = (unsigned short)f2bs(v.y);
        o.z = (unsigned short)f2bs(v.z);
        o.w = (unsigned short)f2bs(v.w);
        *(ushort4*)(xb + off) = o;
        return;
    }

    // transpose path
    const int idx = i - 4096;            // 0..1023
    const int z  = idx >> 8;             // weight select
    const int k0 = (idx & 15) * 64;
    const int n0 = ((idx >> 4) & 15) * 64;
    const float* in = (z == 0) ? w0 : (z == 1) ? w1 : (z == 2) ? w2 : w3;
    short* out = WT + (size_t)z * 1024 * 1024;
    #pragma unroll
    for (int it = 0; it < 4; ++it) {
        const int s = it * 256 + t;
        const int r = s >> 4, c = (s & 15) * 4;
        *(float4*)&T[r][c] = *(const float4*)(in + (size_t)(k0 + r) * 1024 + n0 + c);
    }
    __syncthreads();
    #pragma unroll
    for (int it = 0; it < 4; ++it) {
        const int s = it * 256 + t;
        const int rr = s >> 4, cc = (s & 15) * 4;   // rr: n-local, cc: k-local
        ushort4 o;
        o.x = (unsigned short)f2bs(T[cc + 0][rr]);
        o.y = (unsigned short)f2bs(T[cc + 1][rr]);
        o.z = (unsigned short)f2bs(T[cc + 2][rr]);
        o.w = (unsigned short)f2bs(T[cc + 3][rr]);
        *(ushort4*)(out + (size_t)(n0 + rr) * 1024 + k0 + cc) = o;
    }
}

// ---------------------------------------------------------------------------
// MFMA GEMM (m97 structure): C[z] = (A @ BT[z]^T + bias[z]) * (z==0 ? sc0 : 1)
// 128x128 tile, BK=64, 256 thr = 4 waves of 64x64.
// sc0 folds the attention softmax scale (0.125*log2e) into Q at no cost.
// Grid (8,32,z): HW flat id % 8 == blockIdx.x, so each XCD naturally owns one
// 128-col B panel for all z -- L2-local without an explicit swizzle.
// ---------------------------------------------------------------------------
__global__ __launch_bounds__(256, 3) void gemm_bt(
    const short* __restrict__ A, const short* __restrict__ BTbase,
    const float* __restrict__ b0, const float* __restrict__ b1,
    const float* __restrict__ b2, short* __restrict__ Cbase,
    const float sc0)
{
    __shared__ __align__(16) short As[128 * 64];
    __shared__ __align__(16) short Bs[128 * 64];

    const int z = blockIdx.z;
    const short* BT = BTbase + (size_t)z * 1024 * 1024;
    const float* bias = (z == 0) ? b0 : (z == 1) ? b1 : b2;
    const float sc = (z == 0) ? sc0 : 1.0f;
    short* C = Cbase + (size_t)z * BS * Dc;

    const int t = threadIdx.x;
    const int lane = t & 63, w = t >> 6;
    const int quad = lane >> 4, l16 = lane & 15;
    const int wm = (w & 1) * 64, wn = (w >> 1) * 64;
    const int row0 = blockIdx.y * 128;
    const int col0 = blockIdx.x * 128;
    const int sw = l16 & 7;   // fragment-read swizzle key (row & 7)

    f32x4 acc[4][4] = {};

    for (int kt = 0; kt < 1024; kt += 64) {
        __syncthreads();
        #pragma unroll
        for (int i = 0; i < 4; ++i) {
            const int f = i * 256 + t;            // 16B slot index 0..1023
            const int r = f >> 3;                 // tile row 0..127
            const int g = (f & 7) ^ (r & 7);      // swizzled global seg
            short* lb = &As[(i * 256 + w * 64) * 8];   // wave-uniform base
            gl_lds16(A + (size_t)(row0 + r) * 1024 + kt + g * 8, lb);
            short* lb2 = &Bs[(i * 256 + w * 64) * 8];
            gl_lds16(BT + (size_t)(col0 + r) * 1024 + kt + g * 8, lb2);
        }
        __syncthreads();   // drains vmcnt before use
        #pragma unroll
        for (int ks = 0; ks < 2; ++ks) {
            bf16x8 av[4], bv[4];
            #pragma unroll
            for (int mt = 0; mt < 4; ++mt) {
                const int r = wm + mt * 16 + l16;
                av[mt] = *(const bf16x8*)&As[r * 64 + ((ks * 4 + quad) ^ sw) * 8];
            }
            #pragma unroll
            for (int nt = 0; nt < 4; ++nt) {
                const int r = wn + nt * 16 + l16;
                bv[nt] = *(const bf16x8*)&Bs[r * 64 + ((ks * 4 + quad) ^ sw) * 8];
            }
            #pragma unroll
            for (int mt = 0; mt < 4; ++mt)
                #pragma unroll
                for (int nt = 0; nt < 4; ++nt)
                    acc[mt][nt] = __builtin_amdgcn_mfma_f32_16x16x32_bf16(
                        av[mt], bv[nt], acc[mt][nt], 0, 0, 0);
        }
    }

    float bvv[4];
    #pragma unroll
    for (int nt = 0; nt < 4; ++nt) bvv[nt] = bias[col0 + wn + nt * 16 + l16];
    #pragma unroll
    for (int mt = 0; mt < 4; ++mt)
        #pragma unroll
        for (int reg = 0; reg < 4; ++reg) {
            const size_t row = row0 + wm + mt * 16 + quad * 4 + reg;
            #pragma unroll
            for (int nt = 0; nt < 4; ++nt) {
                const int col = col0 + wn + nt * 16 + l16;
                C[row * 1024 + col] = f2bs((acc[mt][nt][reg] + bvv[nt]) * sc);
            }
        }
}

// ---------------------------------------------------------------------------
// Key permutation pi(k) = (k&15)*4 + (k>>4), applied identically to the key
// axis of P and of VsT (sum over k is order-agnostic). Under pi, a thread's
// 4 P-values per output row become phys cols 4*l16+{0..3} -> one
// ds_write_b64 per row + packed cvt instead of 16 b16 writes + 16 RNE chains.
// NOTE (R8 post-mortem): kf/pf/vf b128 reads are at the LDS data-volume
// minimum (8 dword-accesses/bank, uniformly distributed) -- the residual
// SQ_LDS_BANK_CONFLICT is structural; do not chase it further.
// ---------------------------------------------------------------------------

// softmax(step) + PV for one 16-row q-fragment vs a staged 64-key tile.
// Q is PRE-SCALED by 0.125*log2e in gemm_bt, so scores feed exp2 directly.
// DIAG: only the diagonal tile applies the strict-upper (col > row) mask.
// l-accumulation on the matrix pipe: lacc = mfma(pf, ones, lacc).
// Layouts (HW-validated): A-frag A[m=l16][k=quad*8+j]; B-frag
// B[k=quad*8+j][n=l16]; C/D row=quad*4+reg, col=l16.
template<bool DIAG>
__device__ __forceinline__ void qtile_step(
    const bf16x8 (&qf)[2],
    const short (&Ks)[64][72], const short (&VsT)[64][72],
    short (&Psw)[16][72],
    const int k0, const int row_base,
    const int quad, const int l16,
    const bf16x8 ones,
    f32x4 &lacc, f32x4 (&O)[4])
{
    bf16x8 kf[2][4];
    #pragma unroll
    for (int ks = 0; ks < 2; ++ks)
        #pragma unroll
        for (int nt = 0; nt < 4; ++nt)
            kf[ks][nt] = *(const bf16x8*)&Ks[nt * 16 + l16][ks * 32 + quad * 8];

    f32x4 S[4] = {};
    __builtin_amdgcn_s_setprio(1);
    #pragma unroll
    for (int ks = 0; ks < 2; ++ks)
        #pragma unroll
        for (int nt = 0; nt < 4; ++nt)
            S[nt] = __builtin_amdgcn_mfma_f32_16x16x32_bf16(qf[ks], kf[ks][nt], S[nt], 0, 0, 0);
    __builtin_amdgcn_s_setprio(0);

    // clamp 115.4 == old exp(<=80); mask -126 -> 2^-126 ~= old exp(-87).
    #pragma unroll
    for (int nt = 0; nt < 4; ++nt) {
        #pragma unroll
        for (int reg = 0; reg < 4; ++reg) {
            float s = fminf(S[nt][reg], 115.4f);
            if (DIAG) {
                const int col = k0 + nt * 16 + l16;
                const int row = row_base + quad * 4 + reg;
                s = (col > row) ? s : -126.0f;
            }
            S[nt][reg] = exp2f(s);
        }
    }

    // publish P: per output row, pack 4 values (phys cols 4*l16+0..3) -> b64
    #pragma unroll
    for (int reg = 0; reg < 4; ++reg) {
        const __hip_bfloat162 lo = __float22bfloat162_rn(make_float2(S[0][reg], S[1][reg]));
        const __hip_bfloat162 hi = __float22bfloat162_rn(make_float2(S[2][reg], S[3][reg]));
        uint2 u;
        u.x = *reinterpret_cast<const unsigned int*>(&lo);
        u.y = *reinterpret_cast<const unsigned int*>(&hi);
        *(uint2*)&Psw[quad * 4 + reg][l16 * 4] = u;
    }

    __builtin_amdgcn_s_setprio(1);
    #pragma unroll
    for (int ks = 0; ks < 2; ++ks) {
        const bf16x8 pf = *(const bf16x8*)&Psw[l16][ks * 32 + quad * 8];
        lacc = __builtin_amdgcn_mfma_f32_16x16x32_bf16(pf, ones, lacc, 0, 0, 0);
        #pragma unroll
        for (int nt = 0; nt < 4; ++nt) {
            const bf16x8 vf = *(const bf16x8*)&VsT[nt * 16 + l16][ks * 32 + quad * 8];
            O[nt] = __builtin_amdgcn_mfma_f32_16x16x32_bf16(pf, vf, O[nt], 0, 0, 0);
        }
    }
    __builtin_amdgcn_s_setprio(0);
}

// ---------------------------------------------------------------------------
// Pair-SEQUENTIAL MFMA flash attention (R2/R8 structure, measured best),
// strict-upper mask (attend j > i), WITH vmean fused as concurrent blocks.
// Grid (16,17,2): y<16 -> attn (512 blocks, uniform 33 tiles each);
// y==16 -> vmean for (h=blockIdx.x, b=blockIdx.z), 32 blocks, runs
// concurrently (depends only on V, ready before this launch) and its
// ~6-10us + launch latency hides entirely under attn's 57us.
// Attn skips the row S-1 store (one predicate) so vmean's uniform-softmax
// result ctx = mean_j V is never clobbered (row S-1 is fully masked ->
// reference softmax is exactly uniform).
// XCD ownership for the (16,17,2) grid: HW flat = x+16y+272z -> xcd = x&7
// (y,z terms are multiples of 8); local=(x>>3)+2y+32z in [0,64) -> each XCD
// owns 4 complete (b,h) groups (bh = xcd*4 + local>>4), all 16 pairs.
// Bijective; same distribution & FETCH behavior as R8 (12.3MB).
// ---------------------------------------------------------------------------
__global__ __launch_bounds__(256, 3) void attn_mfma(
    const short* __restrict__ Qg, const short* __restrict__ Kg,
    const short* __restrict__ Vg, short* __restrict__ CTX)
{
    __shared__ __align__(16) short Ks [2][64][72];   // [buf][key][d]
    __shared__ __align__(16) short VsT[2][64][72];   // [buf][d][pi(key)]
    __shared__ __align__(16) short Ps[4][16][72];    // per-wave P scratch
    __shared__ float red[4][64];                     // vmean reduction

    const int tid  = threadIdx.x;

    if (blockIdx.y == 16) {   // ---- vmean path (concurrent) ----
        const int h = blockIdx.x, b = blockIdx.z;
        const int dh = tid & 63, ck = tid >> 6;      // 4 chunks of 512 keys
        float s = 0.f;
        const short* vp = Vg + ((size_t)b * Sc + ck * 512) * Dc + h * DHc + dh;
        for (int j = 0; j < 512; ++j) s += bs2f(vp[(size_t)j * Dc]);
        red[ck][dh] = s;
        __syncthreads();
        if (ck == 0) {
            const float tot = (red[0][dh] + red[1][dh] + red[2][dh] + red[3][dh]) * (1.f / Sc);
            CTX[((size_t)b * Sc + Sc - 1) * Dc + h * DHc + dh] = f2bs(tot);
        }
        return;
    }

    // ---- attn path ----
    const int lane = tid & 63, w = tid >> 6;         // w 0..3
    const int quad = lane >> 4, l16 = lane & 15;

    // XCD-locality decode (see header comment)
    const int xcd   = blockIdx.x & 7;
    const int local = (blockIdx.x >> 3) + 2 * blockIdx.y + 32 * blockIdx.z;  // 0..63
    const int bh    = xcd * 4 + (local >> 4);
    const int p     = local & 15;
    const int h     = bh & 15;
    const int b     = bh >> 4;
    const size_t rb = (size_t)b * Sc;
    const int cb = h * DHc;

    // staging: 256 threads; thread stages key row skey, d-segs sseg & sseg+32
    const int skey = tid & 63, sseg = (tid >> 6) * 8;
    const int pkey = ((skey & 15) << 2) | (skey >> 4);   // pi(skey)

    bf16x8 ones;
    #pragma unroll
    for (int e = 0; e < 8; ++e) ones[e] = (short)0x3F80;   // bf16 1.0

    const size_t tstride = (size_t)64 * Dc;

    #pragma unroll 1
    for (int ph = 0; ph < 2; ++ph) {
        const int myq = ph ? (NT - 1 - p) : p;   // q-tile index 0..31
        const int t0  = myq;
        const int q0  = myq * 64;

        bf16x8 qf[2];
        {
            const short* qp = Qg + (rb + q0 + w * 16 + l16) * (size_t)Dc + cb + quad * 8;
            qf[0] = *(const bf16x8*)(qp);
            qf[1] = *(const bf16x8*)(qp + 32);
        }
        f32x4 lacc = {};
        f32x4 O[4] = {};

        // strength-reduced staging pointers (advance by 64*Dc per tile)
        const short* kp = Kg + (rb + (size_t)t0 * 64 + skey) * Dc + cb + sseg;
        const short* vp = Vg + (rb + (size_t)t0 * 64 + skey) * Dc + cb + sseg;

        if (ph) __syncthreads();   // phase A waves may still be reading bufs

        {   // stage first tile t0 into buf t0&1
            const int buf = t0 & 1;
            const bf16x8 k0v = *(const bf16x8*)(kp);
            const bf16x8 k1v = *(const bf16x8*)(kp + 32);
            const bf16x8 v0v = *(const bf16x8*)(vp);
            const bf16x8 v1v = *(const bf16x8*)(vp + 32);
            *(bf16x8*)&Ks[buf][skey][sseg]      = k0v;
            *(bf16x8*)&Ks[buf][skey][sseg + 32] = k1v;
            #pragma unroll
            for (int e = 0; e < 8; ++e) {
                VsT[buf][sseg + e][pkey]      = v0v[e];
                VsT[buf][sseg + 32 + e][pkey] = v1v[e];
            }
        }
        __syncthreads();

        for (int t = t0; t < NT; ++t) {
            const int cur = t & 1;
            const bool havenext = (t + 1 < NT);
            bf16x8 pk0, pk1, pv0, pv1;
            if (havenext) {   // register prefetch of tile t+1
                pk0 = *(const bf16x8*)(kp + tstride);
                pk1 = *(const bf16x8*)(kp + tstride + 32);
                pv0 = *(const bf16x8*)(vp + tstride);
                pv1 = *(const bf16x8*)(vp + tstride + 32);
            }

            if (t == t0)
                qtile_step<true >(qf, Ks[cur], VsT[cur], Ps[w],
                                  t * 64, q0 + w * 16, quad, l16, ones, lacc, O);
            else
                qtile_step<false>(qf, Ks[cur], VsT[cur], Ps[w],
                                  t * 64, q0 + w * 16, quad, l16, ones, lacc, O);

            if (havenext) {   // stage tile t+1 into the other buffer, ONE barrier
                const int nb = cur ^ 1;
                *(bf16x8*)&Ks[nb][skey][sseg]      = pk0;
                *(bf16x8*)&Ks[nb][skey][sseg + 32] = pk1;
                #pragma unroll
                for (int e = 0; e < 8; ++e) {
                    VsT[nb][sseg + e][pkey]      = pv0[e];
                    VsT[nb][sseg + 32 + e][pkey] = pv1[e];
                }
                __syncthreads();
            }
            kp += tstride;
            vp += tstride;
        }

        // normalize + store; skip row S-1 (owned by the fused vmean blocks)
        float inv[4];
        #pragma unroll
        for (int reg = 0; reg < 4; ++reg) inv[reg] = 1.0f / lacc[reg];
        #pragma unroll
        for (int nt = 0; nt < 4; ++nt)
            #pragma unroll
            for (int reg = 0; reg < 4; ++reg) {
                const int lr = q0 + w * 16 + quad * 4 + reg;
                if (lr != Sc - 1)
                    CTX[(rb + lr) * Dc + cb + nt * 16 + l16] = f2bs(O[nt][reg] * inv[reg]);
            }
    }
}

// ---------------------------------------------------------------------------
// out = LayerNorm(x + attn_out) * gamma + beta; x f32, AO bf16, out f32
// ---------------------------------------------------------------------------
__global__ __launch_bounds__(256, 4) void resid_ln(
    const float* __restrict__ X, const short* __restrict__ AO,
    const float* __restrict__ gamma, const float* __restrict__ beta,
    float* __restrict__ out)
{
    const int r = blockIdx.x;
    const int t = threadIdx.x;
    const size_t base = (size_t)r * Dc + t * 4;

    const float4 x4 = *(const float4*)(X + base);
    const ushort4 a4 = *(const ushort4*)(AO + base);
    float y[4];
    y[0] = x4.x + bs2f(a4.x);
    y[1] = x4.y + bs2f(a4.y);
    y[2] = x4.z + bs2f(a4.z);
    y[3] = x4.w + bs2f(a4.w);

    float s  = y[0] + y[1] + y[2] + y[3];
    float s2 = y[0]*y[0] + y[1]*y[1] + y[2]*y[2] + y[3]*y[3];
    #pragma unroll
    for (int off = 1; off < 64; off <<= 1) {
        s  += __shfl_xor(s,  off, 64);
        s2 += __shfl_xor(s2, off, 64);
    }
    __shared__ float red[8];
    const int w = t >> 6;
    if ((t & 63) == 0) { red[w] = s; red[4 + w] = s2; }
    __syncthreads();
    s  = red[0] + red[1] + red[2] + red[3];
    s2 = red[4] + red[5] + red[6] + red[7];

    const float mu   = s * (1.0f / Dc);
    const float rstd = rsqrtf(s2 * (1.0f / Dc) - mu * mu + 1e-6f);

    const float4 g4 = *(const float4*)(gamma + t * 4);
    const float4 b4 = *(const float4*)(beta  + t * 4);
    float4 o;
    o.x = (y[0] - mu) * rstd * g4.x + b4.x;
    o.y = (y[1] - mu) * rstd * g4.y + b4.y;
    o.z = (y[2] - mu) * rstd * g4.z + b4.z;
    o.w = (y[3] - mu) * rstd * g4.w + b4.w;
    *(float4*)(out + base) = o;
}

// ---------------------------------------------------------------------------
extern "C" void kernel_launch(void* const* d_in, const int* in_sizes, int n_in,
                              void* d_out, int out_size, void* d_ws, size_t ws_size,
                              hipStream_t stream)
{
    (void)in_sizes; (void)n_in; (void)out_size; (void)ws_size;
    const float* x     = (const float*)d_in[0];
    const float* Wq    = (const float*)d_in[1];
    const float* bq    = (const float*)d_in[2];
    const float* Wk    = (const float*)d_in[3];
    const float* bk    = (const float*)d_in[4];
    const float* Wv    = (const float*)d_in[5];
    const float* bv    = (const float*)d_in[6];
    const float* Wo    = (const float*)d_in[7];
    const float* bo    = (const float*)d_in[8];
    const float* gamma = (const float*)d_in[9];
    const float* beta  = (const float*)d_in[10];
    float* out = (float*)d_out;

    const size_t matN = (size_t)BS * Dc;       // 4,194,304
    const size_t wN   = (size_t)Dc * Dc;       // 1,048,576
    short* xb = (short*)d_ws;                  // 8 MB
    short* WT = xb + matN;                     // 8 MB (4 transposed weights)
    short* Qb = WT + 4 * wN;                   // 8 MB
    short* Kb = Qb + matN;                     // 8 MB
    short* Vb = Kb + matN;                     // 8 MB
    short* Cx = Vb + matN;                     // 8 MB
    short* AO = Qb;                            // Q dead after attention

    prep<<<5120, 256, 0, stream>>>(x, xb, Wq, Wk, Wv, Wo, WT);

    dim3 gq(Dc / 128, BS / 128, 3);            // (8, 32, 3)
    gemm_bt<<<gq, 256, 0, stream>>>(xb, WT, bq, bk, bv, Qb, 0.18033688f);

    dim3 ga(16, 17, 2);                        // 512 attn blocks + 32 fused vmean
    attn_mfma<<<ga, 256, 0, stream>>>(Qb, Kb, Vb, Cx);

    dim3 go(Dc / 128, BS / 128, 1);
    gemm_bt<<<go, 256, 0, stream>>>(Cx, WT + 3 * wN, bo, bo, bo, AO, 1.0f);

    resid_ln<<<BS, 256, 0, stream>>>(x, AO, gamma, beta, out);
}